// Round 5
// baseline (117.355 us; speedup 1.0000x reference)
//
#include <hip/hip_runtime.h>

#define E_DIM 69120
#define N1 60
#define H 32
#define CC 3
#define TEB 64
#define NB2 (E_DIM / TEB)   // 1080
#define SBT 66              // bufT row stride (floats): 8B-aligned rows, 2-way max
#define PSZ (N1 * H)        // 1920

// LDS (floats): bufA[64][33] @0  (bufT[32][66] overlays it)
//               bufB[64][33] @2112 (u_l[60][32] overlays it in kCf)
#define LDS_FLOATS 4224     // 16896 B -> 4 blocks/CU (wave-limited)

// =====================================================================
// kA5: v_bar chain + alpha partials.  512 thr: (eLoc 0..63, hg 0..7)
// =====================================================================
template<bool ATOMIC>
__global__ __launch_bounds__(512, 4) void kA5(
    const float* __restrict__ d,
    const float* __restrict__ Wfvb, const float* __restrict__ bfvb,
    const float* __restrict__ Wgvb, const float* __restrict__ bgvb,
    const float* __restrict__ Wfu,  const float* __restrict__ bfu,
    float* __restrict__ outp)
{
    __shared__ __align__(16) float smem[LDS_FLOATS];
    float* bufA = smem;          // [64][33]
    float* bufB = smem + 2112;   // [64][33]
    float* bufT = smem;          // [32][66] overlays bufA
    const int tid = threadIdx.x;
    const long sE = (long)blockIdx.x * TEB;
    const int eLoc = tid & 63, h0 = (tid >> 6) * 4;

    // stage 1: t1 = mean_n relu(d*wf + bf); d read DIRECT from global (L1/L2)
    {
        float wf[4], bf[4], t1[4];
        #pragma unroll
        for (int j = 0; j < 4; ++j) { wf[j] = Wfvb[h0+j]; bf[j] = bfvb[h0+j]; t1[j] = 0.f; }
        const float* dp = d + sE + eLoc;
        #pragma unroll 4
        for (int n = 0; n < N1; ++n) {
            const float dv = dp[(long)n * E_DIM];
            #pragma unroll
            for (int j = 0; j < 4; ++j) t1[j] += fmaxf(fmaf(dv, wf[j], bf[j]), 0.f);
        }
        #pragma unroll
        for (int j = 0; j < 4; ++j) bufA[eLoc * 33 + h0 + j] = t1[j] * (1.f / N1);
    }
    __syncthreads();

    // mv1: vb = relu(t1 @ Wgvb + bgvb) -> bufB
    {
        float acc[4];
        #pragma unroll
        for (int j = 0; j < 4; ++j) acc[j] = bgvb[h0+j];
        #pragma unroll
        for (int k = 0; k < H; ++k) {
            const float t = bufA[eLoc * 33 + k];
            #pragma unroll
            for (int j = 0; j < 4; ++j) acc[j] = fmaf(t, Wgvb[k*H + h0+j], acc[j]);
        }
        #pragma unroll
        for (int j = 0; j < 4; ++j) bufB[eLoc * 33 + h0 + j] = fmaxf(acc[j], 0.f);
    }
    __syncthreads();

    // mv2: vw = vb @ Wu_v + b_fu -> bufT (transposed; bufA dead)
    {
        float acc[4];
        #pragma unroll
        for (int j = 0; j < 4; ++j) acc[j] = bfu[h0+j];
        #pragma unroll
        for (int k = 0; k < H; ++k) {
            const float t = bufB[eLoc * 33 + k];
            #pragma unroll
            for (int j = 0; j < 4; ++j) acc[j] = fmaf(t, Wfu[k*H + h0+j], acc[j]);
        }
        #pragma unroll
        for (int j = 0; j < 4; ++j) bufT[(h0+j) * SBT + eLoc] = acc[j];
    }
    __syncthreads();

    // stage 2: alpha partials; threads (n 0..59, hb 0..7 -> 4 h each)
    if (tid < N1 * 8) {
        const int n = tid >> 3, hb4 = (tid & 7) * 4;
        float wud[4], acc[4];
        #pragma unroll
        for (int j = 0; j < 4; ++j) { wud[j] = Wfu[H*H + hb4 + j]; acc[j] = 0.f; }
        const float* drow = d + (long)n * E_DIM + sE;
        for (int e4 = 0; e4 < TEB; e4 += 4) {
            const float4 d4 = *(const float4*)(drow + e4);
            #pragma unroll
            for (int j = 0; j < 4; ++j) {
                const float* wr = bufT + (hb4 + j) * SBT + e4;
                const float2 wa = *(const float2*)(wr);
                const float2 wb = *(const float2*)(wr + 2);
                acc[j] += fmaxf(fmaf(d4.x, wud[j], wa.x), 0.f)
                        + fmaxf(fmaf(d4.y, wud[j], wa.y), 0.f)
                        + fmaxf(fmaf(d4.z, wud[j], wb.x), 0.f)
                        + fmaxf(fmaf(d4.w, wud[j], wb.y), 0.f);
            }
        }
        if (ATOMIC) {
            float* p = outp + n * H + hb4;
            #pragma unroll
            for (int j = 0; j < 4; ++j) atomicAdd(&p[j], acc[j]);
        } else {
            *(float4*)(outp + (long)blockIdx.x * PSZ + n * H + hb4) =
                make_float4(acc[0], acc[1], acc[2], acc[3]);
        }
    }
}

// =====================================================================
// kCf5: fused v-chain + z partials
// =====================================================================
template<bool ATOMIC>
__global__ __launch_bounds__(512, 4) void kCf5(
    const float* __restrict__ d, const float* __restrict__ d2,
    const float* __restrict__ uwb,
    const float* __restrict__ Wfvc,
    const float* __restrict__ Wgvc, const float* __restrict__ bgvc,
    const float* __restrict__ Wfz,  const float* __restrict__ bfz,
    float* __restrict__ outp)
{
    __shared__ __align__(16) float smem[LDS_FLOATS];
    float* bufA = smem;          // [64][33]
    float* bufB = smem + 2112;   // [64][33]
    float* u_l  = smem + 2112;   // [60][32] overlays bufB (dead before mv1 writes)
    float* bufT = smem;          // [32][66] overlays bufA
    const int tid = threadIdx.x;
    const long sE = (long)blockIdx.x * TEB;
    const int eLoc = tid & 63, h0 = (tid >> 6) * 4;

    if (tid < PSZ / 4)
        ((float4*)u_l)[tid] = ((const float4*)uwb)[tid];
    __syncthreads();

    // stage 1: m = mean_n relu(d*wv_d + u_n)
    {
        float wvd[4], m[4];
        #pragma unroll
        for (int j = 0; j < 4; ++j) { wvd[j] = Wfvc[H*H + h0+j]; m[j] = 0.f; }
        const float* dp = d + sE + eLoc;
        #pragma unroll 4
        for (int n = 0; n < N1; ++n) {
            const float dv = dp[(long)n * E_DIM];
            const float4 u4 = *(const float4*)(u_l + n * H + h0);
            m[0] += fmaxf(fmaf(dv, wvd[0], u4.x), 0.f);
            m[1] += fmaxf(fmaf(dv, wvd[1], u4.y), 0.f);
            m[2] += fmaxf(fmaf(dv, wvd[2], u4.z), 0.f);
            m[3] += fmaxf(fmaf(dv, wvd[3], u4.w), 0.f);
        }
        #pragma unroll
        for (int j = 0; j < 4; ++j) bufA[eLoc * 33 + h0 + j] = m[j] * (1.f / N1);
    }
    __syncthreads();

    // mv1: v = relu(m @ Wgvc + bgvc) -> bufB (u_l dead)
    {
        float acc[4];
        #pragma unroll
        for (int j = 0; j < 4; ++j) acc[j] = bgvc[h0+j];
        #pragma unroll
        for (int k = 0; k < H; ++k) {
            const float t = bufA[eLoc * 33 + k];
            #pragma unroll
            for (int j = 0; j < 4; ++j) acc[j] = fmaf(t, Wgvc[k*H + h0+j], acc[j]);
        }
        #pragma unroll
        for (int j = 0; j < 4; ++j) bufB[eLoc * 33 + h0 + j] = fmaxf(acc[j], 0.f);
    }
    __syncthreads();

    // mv2: vz = v @ Wz_v + b_fz -> bufT (bufA dead)
    {
        float acc[4];
        #pragma unroll
        for (int j = 0; j < 4; ++j) acc[j] = bfz[h0+j];
        #pragma unroll
        for (int k = 0; k < H; ++k) {
            const float t = bufB[eLoc * 33 + k];
            #pragma unroll
            for (int j = 0; j < 4; ++j) acc[j] = fmaf(t, Wfz[k*H + h0+j], acc[j]);
        }
        #pragma unroll
        for (int j = 0; j < 4; ++j) bufT[(h0+j) * SBT + eLoc] = acc[j];
    }
    __syncthreads();

    // stage 2: z partials over QUERY rows
    if (tid < N1 * 8) {
        const int n = tid >> 3, hb4 = (tid & 7) * 4;
        float wzd[4], acc[4];
        #pragma unroll
        for (int j = 0; j < 4; ++j) { wzd[j] = Wfz[H*H + hb4 + j]; acc[j] = 0.f; }
        const float* drow = d2 + (long)n * E_DIM + sE;
        for (int e4 = 0; e4 < TEB; e4 += 4) {
            const float4 d4 = *(const float4*)(drow + e4);
            #pragma unroll
            for (int j = 0; j < 4; ++j) {
                const float* wr = bufT + (hb4 + j) * SBT + e4;
                const float2 wa = *(const float2*)(wr);
                const float2 wb = *(const float2*)(wr + 2);
                acc[j] += fmaxf(fmaf(d4.x, wzd[j], wa.x), 0.f)
                        + fmaxf(fmaf(d4.y, wzd[j], wa.y), 0.f)
                        + fmaxf(fmaf(d4.z, wzd[j], wb.x), 0.f)
                        + fmaxf(fmaf(d4.w, wzd[j], wb.y), 0.f);
            }
        }
        if (ATOMIC) {
            float* p = outp + n * H + hb4;
            #pragma unroll
            for (int j = 0; j < 4; ++j) atomicAdd(&p[j], acc[j]);
        } else {
            *(float4*)(outp + (long)blockIdx.x * PSZ + n * H + hb4) =
                make_float4(acc[0], acc[1], acc[2], acc[3]);
        }
    }
}

// reduce part[NB2][PSZ] -> out[PSZ]; grid = PSZ/16 = 120 blocks
__global__ __launch_bounds__(256) void kR(
    const float* __restrict__ part, float* __restrict__ out)
{
    __shared__ float red[16][17];
    const int tid = threadIdx.x;
    const int oLoc = tid & 15, c = tid >> 4;
    const int o = blockIdx.x * 16 + oLoc;
    const int b0 = c * 68;
    const int bN = (NB2 - b0 < 68) ? (NB2 - b0) : 68;
    const float* p = part + (long)b0 * PSZ + o;
    float s = 0.f;
    #pragma unroll 4
    for (int b = 0; b < bN; ++b) s += p[(long)b * PSZ];
    red[c][oLoc] = s;
    __syncthreads();
    if (tid < 16) {
        float t = 0.f;
        #pragma unroll
        for (int ci = 0; ci < 16; ++ci) t += red[ci][tid];
        out[blockIdx.x * 16 + tid] = t;
    }
}

__global__ __launch_bounds__(1024) void kB(
    const float* __restrict__ alphaAcc, const int* __restrict__ label,
    const float* __restrict__ Wfvb, const float* __restrict__ bfvb,
    const float* __restrict__ Wgvb, const float* __restrict__ bgvb,
    const float* __restrict__ Wfu,  const float* __restrict__ bfu,
    const float* __restrict__ Wgu,  const float* __restrict__ bgu,
    const float* __restrict__ Wfvc, const float* __restrict__ bfvc,
    float* __restrict__ uwb)
{
    __shared__ float up_l[N1 * H];
    __shared__ float un_l[N1 * H];
    __shared__ float cb_l[CC * H];
    __shared__ float cw_l[CC * H];
    __shared__ int   cnt[CC];
    const int tid = threadIdx.x;

    if (tid < CC) cnt[tid] = 0;
    __syncthreads();
    if (tid < N1) atomicAdd(&cnt[label[tid]], 1);
    __syncthreads();

    if (tid < CC * H) {
        const int c = tid / H, h = tid % H;
        const float nc = (float)cnt[c];
        float s = bgvb[h];
        #pragma unroll
        for (int k = 0; k < H; ++k) {
            const float t1c = (nc * fmaxf(Wfvb[k] + bfvb[k], 0.f) +
                               ((float)N1 - nc) * fmaxf(bfvb[k], 0.f)) * (1.f / N1);
            s = fmaf(t1c, Wgvb[k * H + h], s);
        }
        cb_l[tid] = fmaxf(s, 0.f);
    }
    __syncthreads();
    if (tid < CC * H) {
        const int c = tid / H, h = tid % H;
        float s = bfu[h];
        #pragma unroll
        for (int k = 0; k < H; ++k) s = fmaf(cb_l[c * H + k], Wfu[k * H + h], s);
        cw_l[tid] = s;
    }
    __syncthreads();
    for (int t = tid; t < N1 * H; t += 1024) {
        const int n = t >> 5, h = t & 31;
        const int ln = label[n];
        const float wud = Wfu[H * H + h];
        float s = 0.f;
        #pragma unroll
        for (int c = 0; c < CC; ++c)
            s += fmaxf(cw_l[c * H + h] + ((c == ln) ? wud : 0.f), 0.f);
        up_l[t] = alphaAcc[t] * (1.f / E_DIM) + s * (1.f / CC);
    }
    __syncthreads();
    for (int t = tid; t < N1 * H; t += 1024) {
        const int n = t >> 5, h = t & 31;
        float s = bgu[h];
        #pragma unroll
        for (int k = 0; k < H; ++k) s = fmaf(up_l[n * H + k], Wgu[k * H + h], s);
        un_l[t] = fmaxf(s, 0.f);
    }
    __syncthreads();
    for (int t = tid; t < N1 * H; t += 1024) {
        const int n = t >> 5, h = t & 31;
        float s = bfvc[h];
        #pragma unroll
        for (int k = 0; k < H; ++k) s = fmaf(un_l[n * H + k], Wfvc[k * H + h], s);
        uwb[t] = s;
    }
}

__global__ __launch_bounds__(1024) void kD(
    const float* __restrict__ zAcc,
    const float* __restrict__ Wgz, const float* __restrict__ bgz,
    float* __restrict__ out)
{
    __shared__ float z_l[N1 * H];
    const int tid = threadIdx.x;
    for (int t = tid; t < N1 * H; t += 1024) z_l[t] = zAcc[t] * (1.f / E_DIM);
    __syncthreads();
    for (int t = tid; t < N1 * H; t += 1024) {
        const int n = t >> 5, h = t & 31;
        float s = bgz[h];
        #pragma unroll
        for (int k = 0; k < H; ++k) s = fmaf(z_l[n * H + k], Wgz[k * H + h], s);
        out[t] = fmaxf(s, 0.f);
    }
}

extern "C" void kernel_launch(void* const* d_in, const int* in_sizes, int n_in,
                              void* d_out, int out_size, void* d_ws, size_t ws_size,
                              hipStream_t stream)
{
    const float* sup  = (const float*)d_in[0];
    const int*   lab  = (const int*)d_in[1];
    const float* qry  = (const float*)d_in[2];
    const float* Wfvb = (const float*)d_in[3];
    const float* bfvb = (const float*)d_in[4];
    const float* Wgvb = (const float*)d_in[5];
    const float* bgvb = (const float*)d_in[6];
    const float* Wfu  = (const float*)d_in[7];
    const float* bfu  = (const float*)d_in[8];
    const float* Wgu  = (const float*)d_in[9];
    const float* bgu  = (const float*)d_in[10];
    const float* Wfvc = (const float*)d_in[11];
    const float* bfvc = (const float*)d_in[12];
    const float* Wgvc = (const float*)d_in[13];
    const float* bgvc = (const float*)d_in[14];
    const float* Wfz  = (const float*)d_in[15];
    const float* bfz  = (const float*)d_in[16];
    const float* Wgz  = (const float*)d_in[17];
    const float* bgz  = (const float*)d_in[18];
    float* out = (float*)d_out;

    float* alphaAcc = (float*)d_ws;
    float* zAcc     = alphaAcc + PSZ;
    float* uwb      = zAcc + PSZ;
    float* partA    = uwb + PSZ;
    float* partZ    = partA + (size_t)NB2 * PSZ;

    const size_t needMain = (3 * (size_t)PSZ + 2 * (size_t)NB2 * PSZ) * sizeof(float);

    if (ws_size >= needMain) {
        kA5<false><<<NB2, 512, 0, stream>>>(sup, Wfvb, bfvb, Wgvb, bgvb, Wfu, bfu, partA);
        kR<<<PSZ / 16, 256, 0, stream>>>(partA, alphaAcc);
        kB<<<1, 1024, 0, stream>>>(alphaAcc, lab, Wfvb, bfvb, Wgvb, bgvb, Wfu, bfu,
                                   Wgu, bgu, Wfvc, bfvc, uwb);
        kCf5<false><<<NB2, 512, 0, stream>>>(sup, qry, uwb, Wfvc, Wgvc, bgvc, Wfz, bfz, partZ);
        kR<<<PSZ / 16, 256, 0, stream>>>(partZ, zAcc);
        kD<<<1, 1024, 0, stream>>>(zAcc, Wgz, bgz, out);
    } else {
        (void)hipMemsetAsync(alphaAcc, 0, 2 * PSZ * sizeof(float), stream);
        kA5<true><<<NB2, 512, 0, stream>>>(sup, Wfvb, bfvb, Wgvb, bgvb, Wfu, bfu, alphaAcc);
        kB<<<1, 1024, 0, stream>>>(alphaAcc, lab, Wfvb, bfvb, Wgvb, bgvb, Wfu, bfu,
                                   Wgu, bgu, Wfvc, bfvc, uwb);
        kCf5<true><<<NB2, 512, 0, stream>>>(sup, qry, uwb, Wfvc, Wgvc, bgvc, Wfz, bfz, zAcc);
        kD<<<1, 1024, 0, stream>>>(zAcc, Wgz, bgz, out);
    }
}

// Round 6
// 109.230 us; speedup vs baseline: 1.0744x; 1.0744x over previous
//
#include <hip/hip_runtime.h>

#define E_DIM 69120
#define N1 60
#define H 32
#define CC 3
#define TEB 64
#define NB2 (E_DIM / TEB)   // 1080
#define SDS 68              // ds tile stride (floats): 16B-aligned rows
#define PST 17              // partial stride per e
#define PWS (64 * PST)      // 1088 floats per wave-partial
#define SBT 66              // bufT row stride
#define PSZ (N1 * H)        // 1920
// chain buffer offsets inside P (floats): bufA@0, bufB@2112, bufT@4224 (P=8704)

// =====================================================================
// kA7: v_bar chain + alpha partials. 512 thr, n-split stage 1.
// =====================================================================
template<bool ATOMIC>
__global__ __launch_bounds__(512, 6) void kA7(
    const float* __restrict__ d,
    const float* __restrict__ Wfvb, const float* __restrict__ bfvb,
    const float* __restrict__ Wgvb, const float* __restrict__ bgvb,
    const float* __restrict__ Wfu,  const float* __restrict__ bfu,
    float* __restrict__ outp)
{
    __shared__ __align__(16) float ds[N1 * SDS];   // 4080 floats
    __shared__ __align__(16) float P[8 * PWS];     // 8704 floats
    const int tid = threadIdx.x;
    const long sE = (long)blockIdx.x * TEB;

    // phase 0: stage support tile (coalesced float4)
    for (int i = tid; i < N1 * (TEB / 4); i += 512) {
        const int n = i >> 4, c = (i & 15) * 4;
        const float4 v = *(const float4*)(d + (long)n * E_DIM + sE + c);
        float* w = ds + n * SDS + c;
        w[0] = v.x; w[1] = v.y; w[2] = v.z; w[3] = v.w;
    }
    __syncthreads();

    const int l = tid & 63, wv = tid >> 6;

    // phase 1: n-split t1 partials (wave: 15 n's x 16 h's)
    {
        const int hb = (wv >> 2) * 16, n0 = wv & 3;
        float wf[16], bf[16], t1[16];
        #pragma unroll
        for (int j = 0; j < 16; ++j) { wf[j] = Wfvb[hb+j]; bf[j] = bfvb[hb+j]; t1[j] = 0.f; }
        #pragma unroll 3
        for (int n = n0; n < N1; n += 4) {
            const float dv = ds[n * SDS + l];
            #pragma unroll
            for (int j = 0; j < 16; ++j) t1[j] += fmaxf(fmaf(dv, wf[j], bf[j]), 0.f);
        }
        float* pw = P + wv * PWS + l * PST;
        #pragma unroll
        for (int j = 0; j < 16; ++j) pw[j] = t1[j];
    }
    __syncthreads();

    // phase 2: reduce partials -> bufA (in-register, then overlay write)
    {
        const int e = tid >> 3, h0 = (tid & 7) * 4;
        float s[4];
        #pragma unroll
        for (int j = 0; j < 4; ++j) {
            const int h = h0 + j, wb = (h >> 4) * 4, hl = h & 15;
            float a = 0.f;
            #pragma unroll
            for (int q = 0; q < 4; ++q) a += P[(wb + q) * PWS + e * PST + hl];
            s[j] = a * (1.f / N1);
        }
        __syncthreads();
        #pragma unroll
        for (int j = 0; j < 4; ++j) P[e * 33 + h0 + j] = s[j];
    }
    __syncthreads();

    const int eL = tid & 63, h0m = (tid >> 6) * 4;

    // phase 3: vb = relu(t1 @ Wgvb + bgvb) -> bufB
    {
        float acc[4];
        #pragma unroll
        for (int j = 0; j < 4; ++j) acc[j] = bgvb[h0m + j];
        #pragma unroll
        for (int k = 0; k < H; ++k) {
            const float t = P[eL * 33 + k];
            #pragma unroll
            for (int j = 0; j < 4; ++j) acc[j] = fmaf(t, Wgvb[k * H + h0m + j], acc[j]);
        }
        #pragma unroll
        for (int j = 0; j < 4; ++j) P[2112 + eL * 33 + h0m + j] = fmaxf(acc[j], 0.f);
    }
    __syncthreads();

    // phase 4: vw = vb @ Wu_v + b_fu -> bufT (transposed)
    {
        float acc[4];
        #pragma unroll
        for (int j = 0; j < 4; ++j) acc[j] = bfu[h0m + j];
        #pragma unroll
        for (int k = 0; k < H; ++k) {
            const float t = P[2112 + eL * 33 + k];
            #pragma unroll
            for (int j = 0; j < 4; ++j) acc[j] = fmaf(t, Wfu[k * H + h0m + j], acc[j]);
        }
        #pragma unroll
        for (int j = 0; j < 4; ++j) P[4224 + (h0m + j) * SBT + eL] = acc[j];
    }
    __syncthreads();

    // phase 5: alpha partials (n 0..59, 8 h-groups of 4); d from LDS
    if (tid < N1 * 8) {
        const int n = tid >> 3, hb4 = (tid & 7) * 4;
        float wud[4], acc[4];
        #pragma unroll
        for (int j = 0; j < 4; ++j) { wud[j] = Wfu[H * H + hb4 + j]; acc[j] = 0.f; }
        #pragma unroll 4
        for (int e4 = 0; e4 < TEB; e4 += 4) {
            const float4 d4 = *(const float4*)(ds + n * SDS + e4);
            #pragma unroll
            for (int j = 0; j < 4; ++j) {
                const float* wr = P + 4224 + (hb4 + j) * SBT + e4;
                const float2 wa = *(const float2*)(wr);
                const float2 wb = *(const float2*)(wr + 2);
                acc[j] += fmaxf(fmaf(d4.x, wud[j], wa.x), 0.f)
                        + fmaxf(fmaf(d4.y, wud[j], wa.y), 0.f)
                        + fmaxf(fmaf(d4.z, wud[j], wb.x), 0.f)
                        + fmaxf(fmaf(d4.w, wud[j], wb.y), 0.f);
            }
        }
        if (ATOMIC) {
            float* p = outp + n * H + hb4;
            #pragma unroll
            for (int j = 0; j < 4; ++j) atomicAdd(&p[j], acc[j]);
        } else {
            *(float4*)(outp + (long)blockIdx.x * PSZ + n * H + hb4) =
                make_float4(acc[0], acc[1], acc[2], acc[3]);
        }
    }
}

// =====================================================================
// kCf7: fused v-chain + z partials. Query tile restaged into ds.
// =====================================================================
template<bool ATOMIC>
__global__ __launch_bounds__(512, 4) void kCf7(
    const float* __restrict__ d, const float* __restrict__ d2,
    const float* __restrict__ uwb,
    const float* __restrict__ Wfvc,
    const float* __restrict__ Wgvc, const float* __restrict__ bgvc,
    const float* __restrict__ Wfz,  const float* __restrict__ bfz,
    float* __restrict__ outp)
{
    __shared__ __align__(16) float ds[N1 * SDS];   // 4080
    __shared__ __align__(16) float P[8 * PWS];     // 8704
    __shared__ __align__(16) float u_l[PSZ];       // 1920
    const int tid = threadIdx.x;
    const long sE = (long)blockIdx.x * TEB;

    // phase 0: stage support tile + uwb
    for (int i = tid; i < N1 * (TEB / 4); i += 512) {
        const int n = i >> 4, c = (i & 15) * 4;
        const float4 v = *(const float4*)(d + (long)n * E_DIM + sE + c);
        float* w = ds + n * SDS + c;
        w[0] = v.x; w[1] = v.y; w[2] = v.z; w[3] = v.w;
    }
    if (tid < PSZ / 4)
        ((float4*)u_l)[tid] = ((const float4*)uwb)[tid];
    __syncthreads();

    const int l = tid & 63, wv = tid >> 6;

    // phase 1: n-split m partials
    {
        const int hb = (wv >> 2) * 16, n0 = wv & 3;
        float wvd[16], m[16];
        #pragma unroll
        for (int j = 0; j < 16; ++j) { wvd[j] = Wfvc[H * H + hb + j]; m[j] = 0.f; }
        #pragma unroll 3
        for (int n = n0; n < N1; n += 4) {
            const float dv = ds[n * SDS + l];
            const float* ur = u_l + n * H + hb;
            #pragma unroll
            for (int q = 0; q < 4; ++q) {
                const float4 u4 = *(const float4*)(ur + q * 4);
                m[q*4+0] += fmaxf(fmaf(dv, wvd[q*4+0], u4.x), 0.f);
                m[q*4+1] += fmaxf(fmaf(dv, wvd[q*4+1], u4.y), 0.f);
                m[q*4+2] += fmaxf(fmaf(dv, wvd[q*4+2], u4.z), 0.f);
                m[q*4+3] += fmaxf(fmaf(dv, wvd[q*4+3], u4.w), 0.f);
            }
        }
        float* pw = P + wv * PWS + l * PST;
        #pragma unroll
        for (int j = 0; j < 16; ++j) pw[j] = m[j];
    }
    __syncthreads();

    // phase 2: reduce -> bufA
    {
        const int e = tid >> 3, h0 = (tid & 7) * 4;
        float s[4];
        #pragma unroll
        for (int j = 0; j < 4; ++j) {
            const int h = h0 + j, wb = (h >> 4) * 4, hl = h & 15;
            float a = 0.f;
            #pragma unroll
            for (int q = 0; q < 4; ++q) a += P[(wb + q) * PWS + e * PST + hl];
            s[j] = a * (1.f / N1);
        }
        __syncthreads();
        #pragma unroll
        for (int j = 0; j < 4; ++j) P[e * 33 + h0 + j] = s[j];
    }
    __syncthreads();

    // issue query-tile loads early (land in ds after mv1)
    float4 q0, q1;
    {
        const int n = tid >> 4, c = (tid & 15) * 4;
        q0 = *(const float4*)(d2 + (long)n * E_DIM + sE + c);
        if (tid < 448) {
            const int i1 = tid + 512, n1 = i1 >> 4, c1 = (i1 & 15) * 4;
            q1 = *(const float4*)(d2 + (long)n1 * E_DIM + sE + c1);
        }
    }

    const int eL = tid & 63, h0m = (tid >> 6) * 4;

    // phase 3: v = relu(m @ Wgvc + bgvc) -> bufB
    {
        float acc[4];
        #pragma unroll
        for (int j = 0; j < 4; ++j) acc[j] = bgvc[h0m + j];
        #pragma unroll
        for (int k = 0; k < H; ++k) {
            const float t = P[eL * 33 + k];
            #pragma unroll
            for (int j = 0; j < 4; ++j) acc[j] = fmaf(t, Wgvc[k * H + h0m + j], acc[j]);
        }
        #pragma unroll
        for (int j = 0; j < 4; ++j) P[2112 + eL * 33 + h0m + j] = fmaxf(acc[j], 0.f);
    }
    // write query tile into ds (support reads finished before phase-2 barrier)
    {
        const int n = tid >> 4, c = (tid & 15) * 4;
        float* w = ds + n * SDS + c;
        w[0] = q0.x; w[1] = q0.y; w[2] = q0.z; w[3] = q0.w;
        if (tid < 448) {
            const int i1 = tid + 512, n1 = i1 >> 4, c1 = (i1 & 15) * 4;
            float* w1 = ds + n1 * SDS + c1;
            w1[0] = q1.x; w1[1] = q1.y; w1[2] = q1.z; w1[3] = q1.w;
        }
    }
    __syncthreads();

    // phase 4: vz = v @ Wz_v + b_fz -> bufT
    {
        float acc[4];
        #pragma unroll
        for (int j = 0; j < 4; ++j) acc[j] = bfz[h0m + j];
        #pragma unroll
        for (int k = 0; k < H; ++k) {
            const float t = P[2112 + eL * 33 + k];
            #pragma unroll
            for (int j = 0; j < 4; ++j) acc[j] = fmaf(t, Wfz[k * H + h0m + j], acc[j]);
        }
        #pragma unroll
        for (int j = 0; j < 4; ++j) P[4224 + (h0m + j) * SBT + eL] = acc[j];
    }
    __syncthreads();

    // phase 5: z partials over query rows (from LDS)
    if (tid < N1 * 8) {
        const int n = tid >> 3, hb4 = (tid & 7) * 4;
        float wzd[4], acc[4];
        #pragma unroll
        for (int j = 0; j < 4; ++j) { wzd[j] = Wfz[H * H + hb4 + j]; acc[j] = 0.f; }
        #pragma unroll 4
        for (int e4 = 0; e4 < TEB; e4 += 4) {
            const float4 d4 = *(const float4*)(ds + n * SDS + e4);
            #pragma unroll
            for (int j = 0; j < 4; ++j) {
                const float* wr = P + 4224 + (hb4 + j) * SBT + e4;
                const float2 wa = *(const float2*)(wr);
                const float2 wb = *(const float2*)(wr + 2);
                acc[j] += fmaxf(fmaf(d4.x, wzd[j], wa.x), 0.f)
                        + fmaxf(fmaf(d4.y, wzd[j], wa.y), 0.f)
                        + fmaxf(fmaf(d4.z, wzd[j], wb.x), 0.f)
                        + fmaxf(fmaf(d4.w, wzd[j], wb.y), 0.f);
            }
        }
        if (ATOMIC) {
            float* p = outp + n * H + hb4;
            #pragma unroll
            for (int j = 0; j < 4; ++j) atomicAdd(&p[j], acc[j]);
        } else {
            *(float4*)(outp + (long)blockIdx.x * PSZ + n * H + hb4) =
                make_float4(acc[0], acc[1], acc[2], acc[3]);
        }
    }
}

// reduce part[NB2][PSZ] -> out[PSZ]; grid = PSZ/16 = 120 blocks
__global__ __launch_bounds__(256) void kR(
    const float* __restrict__ part, float* __restrict__ out)
{
    __shared__ float red[16][17];
    const int tid = threadIdx.x;
    const int oLoc = tid & 15, c = tid >> 4;
    const int o = blockIdx.x * 16 + oLoc;
    const int b0 = c * 68;
    const int bN = (NB2 - b0 < 68) ? (NB2 - b0) : 68;
    const float* p = part + (long)b0 * PSZ + o;
    float s = 0.f;
    #pragma unroll 4
    for (int b = 0; b < bN; ++b) s += p[(long)b * PSZ];
    red[c][oLoc] = s;
    __syncthreads();
    if (tid < 16) {
        float t = 0.f;
        #pragma unroll
        for (int ci = 0; ci < 16; ++ci) t += red[ci][tid];
        out[blockIdx.x * 16 + tid] = t;
    }
}

__global__ __launch_bounds__(1024) void kB(
    const float* __restrict__ alphaAcc, const int* __restrict__ label,
    const float* __restrict__ Wfvb, const float* __restrict__ bfvb,
    const float* __restrict__ Wgvb, const float* __restrict__ bgvb,
    const float* __restrict__ Wfu,  const float* __restrict__ bfu,
    const float* __restrict__ Wgu,  const float* __restrict__ bgu,
    const float* __restrict__ Wfvc, const float* __restrict__ bfvc,
    float* __restrict__ uwb)
{
    __shared__ float up_l[N1 * H];
    __shared__ float un_l[N1 * H];
    __shared__ float cb_l[CC * H];
    __shared__ float cw_l[CC * H];
    __shared__ int   cnt[CC];
    const int tid = threadIdx.x;

    if (tid < CC) cnt[tid] = 0;
    __syncthreads();
    if (tid < N1) atomicAdd(&cnt[label[tid]], 1);
    __syncthreads();

    if (tid < CC * H) {
        const int c = tid / H, h = tid % H;
        const float nc = (float)cnt[c];
        float s = bgvb[h];
        #pragma unroll
        for (int k = 0; k < H; ++k) {
            const float t1c = (nc * fmaxf(Wfvb[k] + bfvb[k], 0.f) +
                               ((float)N1 - nc) * fmaxf(bfvb[k], 0.f)) * (1.f / N1);
            s = fmaf(t1c, Wgvb[k * H + h], s);
        }
        cb_l[tid] = fmaxf(s, 0.f);
    }
    __syncthreads();
    if (tid < CC * H) {
        const int c = tid / H, h = tid % H;
        float s = bfu[h];
        #pragma unroll
        for (int k = 0; k < H; ++k) s = fmaf(cb_l[c * H + k], Wfu[k * H + h], s);
        cw_l[tid] = s;
    }
    __syncthreads();
    for (int t = tid; t < N1 * H; t += 1024) {
        const int n = t >> 5, h = t & 31;
        const int ln = label[n];
        const float wud = Wfu[H * H + h];
        float s = 0.f;
        #pragma unroll
        for (int c = 0; c < CC; ++c)
            s += fmaxf(cw_l[c * H + h] + ((c == ln) ? wud : 0.f), 0.f);
        up_l[t] = alphaAcc[t] * (1.f / E_DIM) + s * (1.f / CC);
    }
    __syncthreads();
    for (int t = tid; t < N1 * H; t += 1024) {
        const int n = t >> 5, h = t & 31;
        float s = bgu[h];
        #pragma unroll
        for (int k = 0; k < H; ++k) s = fmaf(up_l[n * H + k], Wgu[k * H + h], s);
        un_l[t] = fmaxf(s, 0.f);
    }
    __syncthreads();
    for (int t = tid; t < N1 * H; t += 1024) {
        const int n = t >> 5, h = t & 31;
        float s = bfvc[h];
        #pragma unroll
        for (int k = 0; k < H; ++k) s = fmaf(un_l[n * H + k], Wfvc[k * H + h], s);
        uwb[t] = s;
    }
}

__global__ __launch_bounds__(1024) void kD(
    const float* __restrict__ zAcc,
    const float* __restrict__ Wgz, const float* __restrict__ bgz,
    float* __restrict__ out)
{
    __shared__ float z_l[N1 * H];
    const int tid = threadIdx.x;
    for (int t = tid; t < N1 * H; t += 1024) z_l[t] = zAcc[t] * (1.f / E_DIM);
    __syncthreads();
    for (int t = tid; t < N1 * H; t += 1024) {
        const int n = t >> 5, h = t & 31;
        float s = bgz[h];
        #pragma unroll
        for (int k = 0; k < H; ++k) s = fmaf(z_l[n * H + k], Wgz[k * H + h], s);
        out[t] = fmaxf(s, 0.f);
    }
}

extern "C" void kernel_launch(void* const* d_in, const int* in_sizes, int n_in,
                              void* d_out, int out_size, void* d_ws, size_t ws_size,
                              hipStream_t stream)
{
    const float* sup  = (const float*)d_in[0];
    const int*   lab  = (const int*)d_in[1];
    const float* qry  = (const float*)d_in[2];
    const float* Wfvb = (const float*)d_in[3];
    const float* bfvb = (const float*)d_in[4];
    const float* Wgvb = (const float*)d_in[5];
    const float* bgvb = (const float*)d_in[6];
    const float* Wfu  = (const float*)d_in[7];
    const float* bfu  = (const float*)d_in[8];
    const float* Wgu  = (const float*)d_in[9];
    const float* bgu  = (const float*)d_in[10];
    const float* Wfvc = (const float*)d_in[11];
    const float* bfvc = (const float*)d_in[12];
    const float* Wgvc = (const float*)d_in[13];
    const float* bgvc = (const float*)d_in[14];
    const float* Wfz  = (const float*)d_in[15];
    const float* bfz  = (const float*)d_in[16];
    const float* Wgz  = (const float*)d_in[17];
    const float* bgz  = (const float*)d_in[18];
    float* out = (float*)d_out;

    float* alphaAcc = (float*)d_ws;
    float* zAcc     = alphaAcc + PSZ;
    float* uwb      = zAcc + PSZ;
    float* partA    = uwb + PSZ;
    float* partZ    = partA + (size_t)NB2 * PSZ;

    const size_t needMain = (3 * (size_t)PSZ + 2 * (size_t)NB2 * PSZ) * sizeof(float);

    if (ws_size >= needMain) {
        kA7<false><<<NB2, 512, 0, stream>>>(sup, Wfvb, bfvb, Wgvb, bgvb, Wfu, bfu, partA);
        kR<<<PSZ / 16, 256, 0, stream>>>(partA, alphaAcc);
        kB<<<1, 1024, 0, stream>>>(alphaAcc, lab, Wfvb, bfvb, Wgvb, bgvb, Wfu, bfu,
                                   Wgu, bgu, Wfvc, bfvc, uwb);
        kCf7<false><<<NB2, 512, 0, stream>>>(sup, qry, uwb, Wfvc, Wgvc, bgvc, Wfz, bfz, partZ);
        kR<<<PSZ / 16, 256, 0, stream>>>(partZ, zAcc);
        kD<<<1, 1024, 0, stream>>>(zAcc, Wgz, bgz, out);
    } else {
        (void)hipMemsetAsync(alphaAcc, 0, 2 * PSZ * sizeof(float), stream);
        kA7<true><<<NB2, 512, 0, stream>>>(sup, Wfvb, bfvb, Wgvb, bgvb, Wfu, bfu, alphaAcc);
        kB<<<1, 1024, 0, stream>>>(alphaAcc, lab, Wfvb, bfvb, Wgvb, bgvb, Wfu, bfu,
                                   Wgu, bgu, Wfvc, bfvc, uwb);
        kCf7<true><<<NB2, 512, 0, stream>>>(sup, qry, uwb, Wfvc, Wgvc, bgvc, Wfz, bfz, zAcc);
        kD<<<1, 1024, 0, stream>>>(zAcc, Wgz, bgz, out);
    }
}

// Round 7
// 108.578 us; speedup vs baseline: 1.0808x; 1.0060x over previous
//
#include <hip/hip_runtime.h>

#define E_DIM 69120
#define N1 60
#define H 32
#define CC 3
#define TEB 64
#define NB2 (E_DIM / TEB)   // 1080
#define SDS 68              // ds tile stride (floats): rows 16B-aligned, +4 banks/row
#define SBT 66              // bufT row stride (floats): 2-way max on b64 reads
#define PSZ (N1 * H)        // 1920

// LDS: ds[60*68]=4080f | bufA[64*33]=2112f (bufT[32*66] overlays) | bufB[64*33]=2112f
// total 8304 floats = 33216 B -> 4 blocks/CU x 8 waves = 32 waves/CU (max)

// =====================================================================
// kA9: v_bar chain + alpha partials. 512 thr = (eLoc 0..63, hg 0..7 -> 4 h)
// =====================================================================
template<bool ATOMIC>
__global__ __launch_bounds__(512, 8) void kA9(
    const float* __restrict__ d,
    const float* __restrict__ Wfvb, const float* __restrict__ bfvb,
    const float* __restrict__ Wgvb, const float* __restrict__ bgvb,
    const float* __restrict__ Wfu,  const float* __restrict__ bfu,
    float* __restrict__ outp)
{
    __shared__ __align__(16) float ds[N1 * SDS];
    __shared__ __align__(16) float bufA[64 * 33];
    __shared__ __align__(16) float bufB[64 * 33];
    float* bufT = bufA;  // [32][SBT] overlay, live after bufA is dead
    const int tid = threadIdx.x;
    const long sE = (long)blockIdx.x * TEB;

    // phase 0: stage support tile (float4 both sides; rows 16B-aligned)
    for (int i = tid; i < N1 * (TEB / 4); i += 512) {
        const int n = i >> 4, c = (i & 15) * 4;
        *(float4*)(ds + n * SDS + c) = *(const float4*)(d + (long)n * E_DIM + sE + c);
    }
    __syncthreads();

    const int eL = tid & 63, h0 = (tid >> 6) * 4;

    // phase 1: t1 = mean_n relu(d*wf + bf), 1/N1 folded into wf,bf
    {
        float wf[4], bf[4], t1[4];
        #pragma unroll
        for (int j = 0; j < 4; ++j) {
            wf[j] = Wfvb[h0 + j] * (1.f / N1);
            bf[j] = bfvb[h0 + j] * (1.f / N1);
            t1[j] = 0.f;
        }
        const float* dp = ds + eL;
        #pragma unroll 4
        for (int n = 0; n < N1; ++n) {
            const float dv = dp[n * SDS];
            #pragma unroll
            for (int j = 0; j < 4; ++j) t1[j] += fmaxf(fmaf(dv, wf[j], bf[j]), 0.f);
        }
        #pragma unroll
        for (int j = 0; j < 4; ++j) bufA[eL * 33 + h0 + j] = t1[j];
    }
    __syncthreads();

    // phase 2: vb = relu(t1 @ Wgvb + bgvb) -> bufB
    {
        float acc[4];
        #pragma unroll
        for (int j = 0; j < 4; ++j) acc[j] = bgvb[h0 + j];
        #pragma unroll
        for (int k = 0; k < H; ++k) {
            const float t = bufA[eL * 33 + k];
            #pragma unroll
            for (int j = 0; j < 4; ++j) acc[j] = fmaf(t, Wgvb[k * H + h0 + j], acc[j]);
        }
        #pragma unroll
        for (int j = 0; j < 4; ++j) bufB[eL * 33 + h0 + j] = fmaxf(acc[j], 0.f);
    }
    __syncthreads();

    // phase 3: vw = vb @ Wu_v + b_fu -> bufT (transposed; bufA dead)
    {
        float acc[4];
        #pragma unroll
        for (int j = 0; j < 4; ++j) acc[j] = bfu[h0 + j];
        #pragma unroll
        for (int k = 0; k < H; ++k) {
            const float t = bufB[eL * 33 + k];
            #pragma unroll
            for (int j = 0; j < 4; ++j) acc[j] = fmaf(t, Wfu[k * H + h0 + j], acc[j]);
        }
        #pragma unroll
        for (int j = 0; j < 4; ++j) bufT[(h0 + j) * SBT + eL] = acc[j];
    }
    __syncthreads();

    // phase 4: alpha partials (n 0..59, 8 h-groups of 4); d + vw both from LDS
    if (tid < N1 * 8) {
        const int n = tid >> 3, hb4 = (tid & 7) * 4;
        float wud[4], acc[4];
        #pragma unroll
        for (int j = 0; j < 4; ++j) { wud[j] = Wfu[H * H + hb4 + j]; acc[j] = 0.f; }
        #pragma unroll 2
        for (int e4 = 0; e4 < TEB; e4 += 4) {
            const float4 d4 = *(const float4*)(ds + n * SDS + e4);
            #pragma unroll
            for (int j = 0; j < 4; ++j) {
                const float* wr = bufT + (hb4 + j) * SBT + e4;
                const float2 wa = *(const float2*)(wr);
                const float2 wb = *(const float2*)(wr + 2);
                acc[j] += fmaxf(fmaf(d4.x, wud[j], wa.x), 0.f)
                        + fmaxf(fmaf(d4.y, wud[j], wa.y), 0.f)
                        + fmaxf(fmaf(d4.z, wud[j], wb.x), 0.f)
                        + fmaxf(fmaf(d4.w, wud[j], wb.y), 0.f);
            }
        }
        if (ATOMIC) {
            float* p = outp + n * H + hb4;
            #pragma unroll
            for (int j = 0; j < 4; ++j) atomicAdd(&p[j], acc[j]);
        } else {
            *(float4*)(outp + (long)blockIdx.x * PSZ + n * H + hb4) =
                make_float4(acc[0], acc[1], acc[2], acc[3]);
        }
    }
}

// =====================================================================
// kCf9: fused v-chain + z partials. Support from LDS; query from global.
// =====================================================================
template<bool ATOMIC>
__global__ __launch_bounds__(512, 8) void kCf9(
    const float* __restrict__ d, const float* __restrict__ d2,
    const float* __restrict__ uwb,
    const float* __restrict__ Wfvc,
    const float* __restrict__ Wgvc, const float* __restrict__ bgvc,
    const float* __restrict__ Wfz,  const float* __restrict__ bfz,
    float* __restrict__ outp)
{
    __shared__ __align__(16) float ds[N1 * SDS];
    __shared__ __align__(16) float bufA[64 * 33];
    __shared__ __align__(16) float bufB[64 * 33];
    float* bufT = bufA;   // overlay
    float* u_l  = bufB;   // [60][32] overlay: read in ph1, dead before ph2 writes bufB
    const int tid = threadIdx.x;
    const long sE = (long)blockIdx.x * TEB;

    // phase 0: stage support tile + uwb (pre-scaled by 1/N1)
    for (int i = tid; i < N1 * (TEB / 4); i += 512) {
        const int n = i >> 4, c = (i & 15) * 4;
        *(float4*)(ds + n * SDS + c) = *(const float4*)(d + (long)n * E_DIM + sE + c);
    }
    if (tid < PSZ / 4) {
        float4 u = ((const float4*)uwb)[tid];
        u.x *= (1.f / N1); u.y *= (1.f / N1); u.z *= (1.f / N1); u.w *= (1.f / N1);
        ((float4*)u_l)[tid] = u;
    }
    __syncthreads();

    const int eL = tid & 63, h0 = (tid >> 6) * 4;

    // phase 1: m = mean_n relu(d*wvd + u); 1/N1 folded into wvd and u
    {
        float wvd[4], m[4];
        #pragma unroll
        for (int j = 0; j < 4; ++j) { wvd[j] = Wfvc[H * H + h0 + j] * (1.f / N1); m[j] = 0.f; }
        const float* dp = ds + eL;
        #pragma unroll 4
        for (int n = 0; n < N1; ++n) {
            const float dv = dp[n * SDS];
            const float4 u4 = *(const float4*)(u_l + n * H + h0);   // wave-uniform: broadcast
            m[0] += fmaxf(fmaf(dv, wvd[0], u4.x), 0.f);
            m[1] += fmaxf(fmaf(dv, wvd[1], u4.y), 0.f);
            m[2] += fmaxf(fmaf(dv, wvd[2], u4.z), 0.f);
            m[3] += fmaxf(fmaf(dv, wvd[3], u4.w), 0.f);
        }
        #pragma unroll
        for (int j = 0; j < 4; ++j) bufA[eL * 33 + h0 + j] = m[j];
    }
    __syncthreads();

    // phase 2: v = relu(m @ Wgvc + bgvc) -> bufB (u_l dead)
    {
        float acc[4];
        #pragma unroll
        for (int j = 0; j < 4; ++j) acc[j] = bgvc[h0 + j];
        #pragma unroll
        for (int k = 0; k < H; ++k) {
            const float t = bufA[eL * 33 + k];
            #pragma unroll
            for (int j = 0; j < 4; ++j) acc[j] = fmaf(t, Wgvc[k * H + h0 + j], acc[j]);
        }
        #pragma unroll
        for (int j = 0; j < 4; ++j) bufB[eL * 33 + h0 + j] = fmaxf(acc[j], 0.f);
    }
    __syncthreads();

    // phase 3: vz = v @ Wz_v + b_fz -> bufT (bufA dead)
    {
        float acc[4];
        #pragma unroll
        for (int j = 0; j < 4; ++j) acc[j] = bfz[h0 + j];
        #pragma unroll
        for (int k = 0; k < H; ++k) {
            const float t = bufB[eL * 33 + k];
            #pragma unroll
            for (int j = 0; j < 4; ++j) acc[j] = fmaf(t, Wfz[k * H + h0 + j], acc[j]);
        }
        #pragma unroll
        for (int j = 0; j < 4; ++j) bufT[(h0 + j) * SBT + eL] = acc[j];
    }
    __syncthreads();

    // phase 4: z partials over query rows (global first-touch, 8-lane broadcast)
    if (tid < N1 * 8) {
        const int n = tid >> 3, hb4 = (tid & 7) * 4;
        float wzd[4], acc[4];
        #pragma unroll
        for (int j = 0; j < 4; ++j) { wzd[j] = Wfz[H * H + hb4 + j]; acc[j] = 0.f; }
        const float* drow = d2 + (long)n * E_DIM + sE;
        #pragma unroll 2
        for (int e4 = 0; e4 < TEB; e4 += 4) {
            const float4 d4 = *(const float4*)(drow + e4);
            #pragma unroll
            for (int j = 0; j < 4; ++j) {
                const float* wr = bufT + (hb4 + j) * SBT + e4;
                const float2 wa = *(const float2*)(wr);
                const float2 wb = *(const float2*)(wr + 2);
                acc[j] += fmaxf(fmaf(d4.x, wzd[j], wa.x), 0.f)
                        + fmaxf(fmaf(d4.y, wzd[j], wa.y), 0.f)
                        + fmaxf(fmaf(d4.z, wzd[j], wb.x), 0.f)
                        + fmaxf(fmaf(d4.w, wzd[j], wb.y), 0.f);
            }
        }
        if (ATOMIC) {
            float* p = outp + n * H + hb4;
            #pragma unroll
            for (int j = 0; j < 4; ++j) atomicAdd(&p[j], acc[j]);
        } else {
            *(float4*)(outp + (long)blockIdx.x * PSZ + n * H + hb4) =
                make_float4(acc[0], acc[1], acc[2], acc[3]);
        }
    }
}

// reduce part[NB2][PSZ] -> out[PSZ]; grid = PSZ/16 = 120 blocks
__global__ __launch_bounds__(256) void kR(
    const float* __restrict__ part, float* __restrict__ out)
{
    __shared__ float red[16][17];
    const int tid = threadIdx.x;
    const int oLoc = tid & 15, c = tid >> 4;
    const int o = blockIdx.x * 16 + oLoc;
    const int b0 = c * 68;
    const int bN = (NB2 - b0 < 68) ? (NB2 - b0) : 68;
    const float* p = part + (long)b0 * PSZ + o;
    float s = 0.f;
    #pragma unroll 4
    for (int b = 0; b < bN; ++b) s += p[(long)b * PSZ];
    red[c][oLoc] = s;
    __syncthreads();
    if (tid < 16) {
        float t = 0.f;
        #pragma unroll
        for (int ci = 0; ci < 16; ++ci) t += red[ci][tid];
        out[blockIdx.x * 16 + tid] = t;
    }
}

__global__ __launch_bounds__(1024) void kB(
    const float* __restrict__ alphaAcc, const int* __restrict__ label,
    const float* __restrict__ Wfvb, const float* __restrict__ bfvb,
    const float* __restrict__ Wgvb, const float* __restrict__ bgvb,
    const float* __restrict__ Wfu,  const float* __restrict__ bfu,
    const float* __restrict__ Wgu,  const float* __restrict__ bgu,
    const float* __restrict__ Wfvc, const float* __restrict__ bfvc,
    float* __restrict__ uwb)
{
    __shared__ float up_l[N1 * H];
    __shared__ float un_l[N1 * H];
    __shared__ float cb_l[CC * H];
    __shared__ float cw_l[CC * H];
    __shared__ int   cnt[CC];
    const int tid = threadIdx.x;

    if (tid < CC) cnt[tid] = 0;
    __syncthreads();
    if (tid < N1) atomicAdd(&cnt[label[tid]], 1);
    __syncthreads();

    if (tid < CC * H) {
        const int c = tid / H, h = tid % H;
        const float nc = (float)cnt[c];
        float s = bgvb[h];
        #pragma unroll
        for (int k = 0; k < H; ++k) {
            const float t1c = (nc * fmaxf(Wfvb[k] + bfvb[k], 0.f) +
                               ((float)N1 - nc) * fmaxf(bfvb[k], 0.f)) * (1.f / N1);
            s = fmaf(t1c, Wgvb[k * H + h], s);
        }
        cb_l[tid] = fmaxf(s, 0.f);
    }
    __syncthreads();
    if (tid < CC * H) {
        const int c = tid / H, h = tid % H;
        float s = bfu[h];
        #pragma unroll
        for (int k = 0; k < H; ++k) s = fmaf(cb_l[c * H + k], Wfu[k * H + h], s);
        cw_l[tid] = s;
    }
    __syncthreads();
    for (int t = tid; t < N1 * H; t += 1024) {
        const int n = t >> 5, h = t & 31;
        const int ln = label[n];
        const float wud = Wfu[H * H + h];
        float s = 0.f;
        #pragma unroll
        for (int c = 0; c < CC; ++c)
            s += fmaxf(cw_l[c * H + h] + ((c == ln) ? wud : 0.f), 0.f);
        up_l[t] = alphaAcc[t] * (1.f / E_DIM) + s * (1.f / CC);
    }
    __syncthreads();
    for (int t = tid; t < N1 * H; t += 1024) {
        const int n = t >> 5, h = t & 31;
        float s = bgu[h];
        #pragma unroll
        for (int k = 0; k < H; ++k) s = fmaf(up_l[n * H + k], Wgu[k * H + h], s);
        un_l[t] = fmaxf(s, 0.f);
    }
    __syncthreads();
    for (int t = tid; t < N1 * H; t += 1024) {
        const int n = t >> 5, h = t & 31;
        float s = bfvc[h];
        #pragma unroll
        for (int k = 0; k < H; ++k) s = fmaf(un_l[n * H + k], Wfvc[k * H + h], s);
        uwb[t] = s;
    }
}

__global__ __launch_bounds__(1024) void kD(
    const float* __restrict__ zAcc,
    const float* __restrict__ Wgz, const float* __restrict__ bgz,
    float* __restrict__ out)
{
    __shared__ float z_l[N1 * H];
    const int tid = threadIdx.x;
    for (int t = tid; t < N1 * H; t += 1024) z_l[t] = zAcc[t] * (1.f / E_DIM);
    __syncthreads();
    for (int t = tid; t < N1 * H; t += 1024) {
        const int n = t >> 5, h = t & 31;
        float s = bgz[h];
        #pragma unroll
        for (int k = 0; k < H; ++k) s = fmaf(z_l[n * H + k], Wgz[k * H + h], s);
        out[t] = fmaxf(s, 0.f);
    }
}

extern "C" void kernel_launch(void* const* d_in, const int* in_sizes, int n_in,
                              void* d_out, int out_size, void* d_ws, size_t ws_size,
                              hipStream_t stream)
{
    const float* sup  = (const float*)d_in[0];
    const int*   lab  = (const int*)d_in[1];
    const float* qry  = (const float*)d_in[2];
    const float* Wfvb = (const float*)d_in[3];
    const float* bfvb = (const float*)d_in[4];
    const float* Wgvb = (const float*)d_in[5];
    const float* bgvb = (const float*)d_in[6];
    const float* Wfu  = (const float*)d_in[7];
    const float* bfu  = (const float*)d_in[8];
    const float* Wgu  = (const float*)d_in[9];
    const float* bgu  = (const float*)d_in[10];
    const float* Wfvc = (const float*)d_in[11];
    const float* bfvc = (const float*)d_in[12];
    const float* Wgvc = (const float*)d_in[13];
    const float* bgvc = (const float*)d_in[14];
    const float* Wfz  = (const float*)d_in[15];
    const float* bfz  = (const float*)d_in[16];
    const float* Wgz  = (const float*)d_in[17];
    const float* bgz  = (const float*)d_in[18];
    float* out = (float*)d_out;

    float* alphaAcc = (float*)d_ws;
    float* zAcc     = alphaAcc + PSZ;
    float* uwb      = zAcc + PSZ;
    float* partA    = uwb + PSZ;
    float* partZ    = partA + (size_t)NB2 * PSZ;

    const size_t needMain = (3 * (size_t)PSZ + 2 * (size_t)NB2 * PSZ) * sizeof(float);

    if (ws_size >= needMain) {
        kA9<false><<<NB2, 512, 0, stream>>>(sup, Wfvb, bfvb, Wgvb, bgvb, Wfu, bfu, partA);
        kR<<<PSZ / 16, 256, 0, stream>>>(partA, alphaAcc);
        kB<<<1, 1024, 0, stream>>>(alphaAcc, lab, Wfvb, bfvb, Wgvb, bgvb, Wfu, bfu,
                                   Wgu, bgu, Wfvc, bfvc, uwb);
        kCf9<false><<<NB2, 512, 0, stream>>>(sup, qry, uwb, Wfvc, Wgvc, bgvc, Wfz, bfz, partZ);
        kR<<<PSZ / 16, 256, 0, stream>>>(partZ, zAcc);
        kD<<<1, 1024, 0, stream>>>(zAcc, Wgz, bgz, out);
    } else {
        (void)hipMemsetAsync(alphaAcc, 0, 2 * PSZ * sizeof(float), stream);
        kA9<true><<<NB2, 512, 0, stream>>>(sup, Wfvb, bfvb, Wgvb, bgvb, Wfu, bfu, alphaAcc);
        kB<<<1, 1024, 0, stream>>>(alphaAcc, lab, Wfvb, bfvb, Wgvb, bgvb, Wfu, bfu,
                                   Wgu, bgu, Wfvc, bfvc, uwb);
        kCf9<true><<<NB2, 512, 0, stream>>>(sup, qry, uwb, Wfvc, Wgvc, bgvc, Wfz, bfz, zAcc);
        kD<<<1, 1024, 0, stream>>>(zAcc, Wgz, bgz, out);
    }
}

// Round 8
// 103.866 us; speedup vs baseline: 1.1299x; 1.0454x over previous
//
#include <hip/hip_runtime.h>

#define E_DIM 69120
#define N1 60
#define H 32
#define CC 3
#define TEB 64
#define NB2 (E_DIM / TEB)   // 1080
#define SDS 68              // ds tile stride (floats)
#define SBA 34              // bufA stride (floats); region 64*34 = 2176
#define SBB 33              // bufB stride
#define SBT 68              // bufT stride (floats, 16B-aligned rows for b128 reads)
#define PSZ (N1 * H)        // 1920

// LDS: ds[60*68]=4080f | bufAT[2176]f (bufA[64][34] / bufT[32][68] overlay)
//      | bufB[64*33]=2112f  -> total 8368 f = 33472 B

__device__ __forceinline__ float relu_dot4(const float4 d, const float w, const float4 t) {
    return fmaxf(fmaf(d.x, w, t.x), 0.f) + fmaxf(fmaf(d.y, w, t.y), 0.f)
         + fmaxf(fmaf(d.z, w, t.z), 0.f) + fmaxf(fmaf(d.w, w, t.w), 0.f);
}

// =====================================================================
// kA11: v_bar chain + alpha partials. 512 thr = (eL 0..63, hg 0..7)
// =====================================================================
template<bool ATOMIC>
__global__ __launch_bounds__(512, 4) void kA11(
    const float* __restrict__ d,
    const float* __restrict__ Wfvb, const float* __restrict__ bfvb,
    const float* __restrict__ Wgvb, const float* __restrict__ bgvb,
    const float* __restrict__ Wfu,  const float* __restrict__ bfu,
    float* __restrict__ outp)
{
    __shared__ __align__(16) float ds[N1 * SDS];
    __shared__ __align__(16) float bufAT[2176];
    __shared__ __align__(16) float bufB[64 * SBB];
    const int tid = threadIdx.x;
    const long sE = (long)blockIdx.x * TEB;

    // phase 0: stage support tile
    for (int i = tid; i < N1 * (TEB / 4); i += 512) {
        const int n = i >> 4, c = (i & 15) * 4;
        *(float4*)(ds + n * SDS + c) = *(const float4*)(d + (long)n * E_DIM + sE + c);
    }
    __syncthreads();

    const int eL = tid & 63, h0 = (tid >> 6) * 4;

    // phase 1: t1 = mean_n relu(d*wf + bf); dual accumulators, 1/N1 folded
    {
        float wf[4], bf[4], ta[4], tb[4];
        #pragma unroll
        for (int j = 0; j < 4; ++j) {
            wf[j] = Wfvb[h0 + j] * (1.f / N1);
            bf[j] = bfvb[h0 + j] * (1.f / N1);
            ta[j] = 0.f; tb[j] = 0.f;
        }
        const float* dp = ds + eL;
        #pragma unroll 6
        for (int n = 0; n < N1; n += 2) {
            const float dv0 = dp[n * SDS];
            const float dv1 = dp[(n + 1) * SDS];
            #pragma unroll
            for (int j = 0; j < 4; ++j) {
                ta[j] += fmaxf(fmaf(dv0, wf[j], bf[j]), 0.f);
                tb[j] += fmaxf(fmaf(dv1, wf[j], bf[j]), 0.f);
            }
        }
        #pragma unroll
        for (int j = 0; j < 4; ++j) bufAT[eL * SBA + h0 + j] = ta[j] + tb[j];
    }
    __syncthreads();

    // phase 2: vb = relu(t1 @ Wgvb + bgvb) -> bufB
    {
        float acc[4];
        #pragma unroll
        for (int j = 0; j < 4; ++j) acc[j] = bgvb[h0 + j];
        #pragma unroll
        for (int k = 0; k < H; ++k) {
            const float t = bufAT[eL * SBA + k];
            #pragma unroll
            for (int j = 0; j < 4; ++j) acc[j] = fmaf(t, Wgvb[k * H + h0 + j], acc[j]);
        }
        #pragma unroll
        for (int j = 0; j < 4; ++j) bufB[eL * SBB + h0 + j] = fmaxf(acc[j], 0.f);
    }
    __syncthreads();

    // phase 3: vw = vb @ Wu_v + b_fu -> bufT (transposed; bufA dead)
    {
        float acc[4];
        #pragma unroll
        for (int j = 0; j < 4; ++j) acc[j] = bfu[h0 + j];
        #pragma unroll
        for (int k = 0; k < H; ++k) {
            const float t = bufB[eL * SBB + k];
            #pragma unroll
            for (int j = 0; j < 4; ++j) acc[j] = fmaf(t, Wfu[k * H + h0 + j], acc[j]);
        }
        #pragma unroll
        for (int j = 0; j < 4; ++j) bufAT[(h0 + j) * SBT + eL] = acc[j];
    }
    __syncthreads();

    // phase 4: alpha partials; d + vw from LDS, b128 reads, unroll x2
    if (tid < N1 * 8) {
        const int n = tid >> 3, hb4 = (tid & 7) * 4;
        float wud[4], acc[4];
        #pragma unroll
        for (int j = 0; j < 4; ++j) { wud[j] = Wfu[H * H + hb4 + j]; acc[j] = 0.f; }
        const float* dsrow = ds + n * SDS;
        for (int e8 = 0; e8 < TEB; e8 += 8) {
            const float4 dA = *(const float4*)(dsrow + e8);
            const float4 dB = *(const float4*)(dsrow + e8 + 4);
            #pragma unroll
            for (int j = 0; j < 4; ++j) {
                const float4 wA = *(const float4*)(bufAT + (hb4 + j) * SBT + e8);
                const float4 wB = *(const float4*)(bufAT + (hb4 + j) * SBT + e8 + 4);
                acc[j] += relu_dot4(dA, wud[j], wA) + relu_dot4(dB, wud[j], wB);
            }
        }
        if (ATOMIC) {
            float* p = outp + n * H + hb4;
            #pragma unroll
            for (int j = 0; j < 4; ++j) atomicAdd(&p[j], acc[j]);
        } else {
            *(float4*)(outp + (long)blockIdx.x * PSZ + n * H + hb4) =
                make_float4(acc[0], acc[1], acc[2], acc[3]);
        }
    }
}

// =====================================================================
// kCf11: fused v-chain + z partials. Support from LDS; query from global.
// =====================================================================
template<bool ATOMIC>
__global__ __launch_bounds__(512, 4) void kCf11(
    const float* __restrict__ d, const float* __restrict__ d2,
    const float* __restrict__ uwb,
    const float* __restrict__ Wfvc,
    const float* __restrict__ Wgvc, const float* __restrict__ bgvc,
    const float* __restrict__ Wfz,  const float* __restrict__ bfz,
    float* __restrict__ outp)
{
    __shared__ __align__(16) float ds[N1 * SDS];
    __shared__ __align__(16) float bufAT[2176];
    __shared__ __align__(16) float bufB[64 * SBB];
    float* u_l = bufB;   // [60][32] overlay: read in ph1, dead before ph2 writes
    const int tid = threadIdx.x;
    const long sE = (long)blockIdx.x * TEB;

    // phase 0: stage support tile + uwb (pre-scaled by 1/N1)
    for (int i = tid; i < N1 * (TEB / 4); i += 512) {
        const int n = i >> 4, c = (i & 15) * 4;
        *(float4*)(ds + n * SDS + c) = *(const float4*)(d + (long)n * E_DIM + sE + c);
    }
    if (tid < PSZ / 4) {
        float4 u = ((const float4*)uwb)[tid];
        u.x *= (1.f / N1); u.y *= (1.f / N1); u.z *= (1.f / N1); u.w *= (1.f / N1);
        ((float4*)u_l)[tid] = u;
    }
    __syncthreads();

    const int eL = tid & 63, h0 = (tid >> 6) * 4;

    // phase 1: m = mean_n relu(d*wvd + u); dual accumulators
    {
        float wvd[4], ma[4], mb[4];
        #pragma unroll
        for (int j = 0; j < 4; ++j) { wvd[j] = Wfvc[H * H + h0 + j] * (1.f / N1); ma[j] = 0.f; mb[j] = 0.f; }
        const float* dp = ds + eL;
        #pragma unroll 6
        for (int n = 0; n < N1; n += 2) {
            const float dv0 = dp[n * SDS];
            const float dv1 = dp[(n + 1) * SDS];
            const float4 u0 = *(const float4*)(u_l + n * H + h0);        // broadcast
            const float4 u1 = *(const float4*)(u_l + (n + 1) * H + h0);  // broadcast
            ma[0] += fmaxf(fmaf(dv0, wvd[0], u0.x), 0.f);
            ma[1] += fmaxf(fmaf(dv0, wvd[1], u0.y), 0.f);
            ma[2] += fmaxf(fmaf(dv0, wvd[2], u0.z), 0.f);
            ma[3] += fmaxf(fmaf(dv0, wvd[3], u0.w), 0.f);
            mb[0] += fmaxf(fmaf(dv1, wvd[0], u1.x), 0.f);
            mb[1] += fmaxf(fmaf(dv1, wvd[1], u1.y), 0.f);
            mb[2] += fmaxf(fmaf(dv1, wvd[2], u1.z), 0.f);
            mb[3] += fmaxf(fmaf(dv1, wvd[3], u1.w), 0.f);
        }
        #pragma unroll
        for (int j = 0; j < 4; ++j) bufAT[eL * SBA + h0 + j] = ma[j] + mb[j];
    }
    __syncthreads();

    // phase 2: v = relu(m @ Wgvc + bgvc) -> bufB (u_l dead)
    {
        float acc[4];
        #pragma unroll
        for (int j = 0; j < 4; ++j) acc[j] = bgvc[h0 + j];
        #pragma unroll
        for (int k = 0; k < H; ++k) {
            const float t = bufAT[eL * SBA + k];
            #pragma unroll
            for (int j = 0; j < 4; ++j) acc[j] = fmaf(t, Wgvc[k * H + h0 + j], acc[j]);
        }
        #pragma unroll
        for (int j = 0; j < 4; ++j) bufB[eL * SBB + h0 + j] = fmaxf(acc[j], 0.f);
    }
    __syncthreads();

    // phase 3: vz = v @ Wz_v + b_fz -> bufT (bufA dead)
    {
        float acc[4];
        #pragma unroll
        for (int j = 0; j < 4; ++j) acc[j] = bfz[h0 + j];
        #pragma unroll
        for (int k = 0; k < H; ++k) {
            const float t = bufB[eL * SBB + k];
            #pragma unroll
            for (int j = 0; j < 4; ++j) acc[j] = fmaf(t, Wfz[k * H + h0 + j], acc[j]);
        }
        #pragma unroll
        for (int j = 0; j < 4; ++j) bufAT[(h0 + j) * SBT + eL] = acc[j];
    }
    __syncthreads();

    // phase 4: z partials over query rows (global first-touch)
    if (tid < N1 * 8) {
        const int n = tid >> 3, hb4 = (tid & 7) * 4;
        float wzd[4], acc[4];
        #pragma unroll
        for (int j = 0; j < 4; ++j) { wzd[j] = Wfz[H * H + hb4 + j]; acc[j] = 0.f; }
        const float* drow = d2 + (long)n * E_DIM + sE;
        for (int e8 = 0; e8 < TEB; e8 += 8) {
            const float4 dA = *(const float4*)(drow + e8);
            const float4 dB = *(const float4*)(drow + e8 + 4);
            #pragma unroll
            for (int j = 0; j < 4; ++j) {
                const float4 wA = *(const float4*)(bufAT + (hb4 + j) * SBT + e8);
                const float4 wB = *(const float4*)(bufAT + (hb4 + j) * SBT + e8 + 4);
                acc[j] += relu_dot4(dA, wzd[j], wA) + relu_dot4(dB, wzd[j], wB);
            }
        }
        if (ATOMIC) {
            float* p = outp + n * H + hb4;
            #pragma unroll
            for (int j = 0; j < 4; ++j) atomicAdd(&p[j], acc[j]);
        } else {
            *(float4*)(outp + (long)blockIdx.x * PSZ + n * H + hb4) =
                make_float4(acc[0], acc[1], acc[2], acc[3]);
        }
    }
}

// reduce part[NB2][PSZ] -> out[PSZ]; grid = PSZ/16 = 120 blocks
__global__ __launch_bounds__(256) void kR(
    const float* __restrict__ part, float* __restrict__ out)
{
    __shared__ float red[16][17];
    const int tid = threadIdx.x;
    const int oLoc = tid & 15, c = tid >> 4;
    const int o = blockIdx.x * 16 + oLoc;
    const int b0 = c * 68;
    const int bN = (NB2 - b0 < 68) ? (NB2 - b0) : 68;
    const float* p = part + (long)b0 * PSZ + o;
    float s = 0.f;
    #pragma unroll 4
    for (int b = 0; b < bN; ++b) s += p[(long)b * PSZ];
    red[c][oLoc] = s;
    __syncthreads();
    if (tid < 16) {
        float t = 0.f;
        #pragma unroll
        for (int ci = 0; ci < 16; ++ci) t += red[ci][tid];
        out[blockIdx.x * 16 + tid] = t;
    }
}

__global__ __launch_bounds__(1024) void kB(
    const float* __restrict__ alphaAcc, const int* __restrict__ label,
    const float* __restrict__ Wfvb, const float* __restrict__ bfvb,
    const float* __restrict__ Wgvb, const float* __restrict__ bgvb,
    const float* __restrict__ Wfu,  const float* __restrict__ bfu,
    const float* __restrict__ Wgu,  const float* __restrict__ bgu,
    const float* __restrict__ Wfvc, const float* __restrict__ bfvc,
    float* __restrict__ uwb)
{
    __shared__ float up_l[N1 * H];
    __shared__ float un_l[N1 * H];
    __shared__ float cb_l[CC * H];
    __shared__ float cw_l[CC * H];
    __shared__ int   cnt[CC];
    const int tid = threadIdx.x;

    if (tid < CC) cnt[tid] = 0;
    __syncthreads();
    if (tid < N1) atomicAdd(&cnt[label[tid]], 1);
    __syncthreads();

    if (tid < CC * H) {
        const int c = tid / H, h = tid % H;
        const float nc = (float)cnt[c];
        float s = bgvb[h];
        #pragma unroll
        for (int k = 0; k < H; ++k) {
            const float t1c = (nc * fmaxf(Wfvb[k] + bfvb[k], 0.f) +
                               ((float)N1 - nc) * fmaxf(bfvb[k], 0.f)) * (1.f / N1);
            s = fmaf(t1c, Wgvb[k * H + h], s);
        }
        cb_l[tid] = fmaxf(s, 0.f);
    }
    __syncthreads();
    if (tid < CC * H) {
        const int c = tid / H, h = tid % H;
        float s = bfu[h];
        #pragma unroll
        for (int k = 0; k < H; ++k) s = fmaf(cb_l[c * H + k], Wfu[k * H + h], s);
        cw_l[tid] = s;
    }
    __syncthreads();
    for (int t = tid; t < N1 * H; t += 1024) {
        const int n = t >> 5, h = t & 31;
        const int ln = label[n];
        const float wud = Wfu[H * H + h];
        float s = 0.f;
        #pragma unroll
        for (int c = 0; c < CC; ++c)
            s += fmaxf(cw_l[c * H + h] + ((c == ln) ? wud : 0.f), 0.f);
        up_l[t] = alphaAcc[t] * (1.f / E_DIM) + s * (1.f / CC);
    }
    __syncthreads();
    for (int t = tid; t < N1 * H; t += 1024) {
        const int n = t >> 5, h = t & 31;
        float s = bgu[h];
        #pragma unroll
        for (int k = 0; k < H; ++k) s = fmaf(up_l[n * H + k], Wgu[k * H + h], s);
        un_l[t] = fmaxf(s, 0.f);
    }
    __syncthreads();
    for (int t = tid; t < N1 * H; t += 1024) {
        const int n = t >> 5, h = t & 31;
        float s = bfvc[h];
        #pragma unroll
        for (int k = 0; k < H; ++k) s = fmaf(un_l[n * H + k], Wfvc[k * H + h], s);
        uwb[t] = s;
    }
}

__global__ __launch_bounds__(1024) void kD(
    const float* __restrict__ zAcc,
    const float* __restrict__ Wgz, const float* __restrict__ bgz,
    float* __restrict__ out)
{
    __shared__ float z_l[N1 * H];
    const int tid = threadIdx.x;
    for (int t = tid; t < N1 * H; t += 1024) z_l[t] = zAcc[t] * (1.f / E_DIM);
    __syncthreads();
    for (int t = tid; t < N1 * H; t += 1024) {
        const int n = t >> 5, h = t & 31;
        float s = bgz[h];
        #pragma unroll
        for (int k = 0; k < H; ++k) s = fmaf(z_l[n * H + k], Wgz[k * H + h], s);
        out[t] = fmaxf(s, 0.f);
    }
}

extern "C" void kernel_launch(void* const* d_in, const int* in_sizes, int n_in,
                              void* d_out, int out_size, void* d_ws, size_t ws_size,
                              hipStream_t stream)
{
    const float* sup  = (const float*)d_in[0];
    const int*   lab  = (const int*)d_in[1];
    const float* qry  = (const float*)d_in[2];
    const float* Wfvb = (const float*)d_in[3];
    const float* bfvb = (const float*)d_in[4];
    const float* Wgvb = (const float*)d_in[5];
    const float* bgvb = (const float*)d_in[6];
    const float* Wfu  = (const float*)d_in[7];
    const float* bfu  = (const float*)d_in[8];
    const float* Wgu  = (const float*)d_in[9];
    const float* bgu  = (const float*)d_in[10];
    const float* Wfvc = (const float*)d_in[11];
    const float* bfvc = (const float*)d_in[12];
    const float* Wgvc = (const float*)d_in[13];
    const float* bgvc = (const float*)d_in[14];
    const float* Wfz  = (const float*)d_in[15];
    const float* bfz  = (const float*)d_in[16];
    const float* Wgz  = (const float*)d_in[17];
    const float* bgz  = (const float*)d_in[18];
    float* out = (float*)d_out;

    float* alphaAcc = (float*)d_ws;
    float* zAcc     = alphaAcc + PSZ;
    float* uwb      = zAcc + PSZ;
    float* partA    = uwb + PSZ;
    float* partZ    = partA + (size_t)NB2 * PSZ;

    const size_t needMain = (3 * (size_t)PSZ + 2 * (size_t)NB2 * PSZ) * sizeof(float);

    if (ws_size >= needMain) {
        kA11<false><<<NB2, 512, 0, stream>>>(sup, Wfvb, bfvb, Wgvb, bgvb, Wfu, bfu, partA);
        kR<<<PSZ / 16, 256, 0, stream>>>(partA, alphaAcc);
        kB<<<1, 1024, 0, stream>>>(alphaAcc, lab, Wfvb, bfvb, Wgvb, bgvb, Wfu, bfu,
                                   Wgu, bgu, Wfvc, bfvc, uwb);
        kCf11<false><<<NB2, 512, 0, stream>>>(sup, qry, uwb, Wfvc, Wgvc, bgvc, Wfz, bfz, partZ);
        kR<<<PSZ / 16, 256, 0, stream>>>(partZ, zAcc);
        kD<<<1, 1024, 0, stream>>>(zAcc, Wgz, bgz, out);
    } else {
        (void)hipMemsetAsync(alphaAcc, 0, 2 * PSZ * sizeof(float), stream);
        kA11<true><<<NB2, 512, 0, stream>>>(sup, Wfvb, bfvb, Wgvb, bgvb, Wfu, bfu, alphaAcc);
        kB<<<1, 1024, 0, stream>>>(alphaAcc, lab, Wfvb, bfvb, Wgvb, bgvb, Wfu, bfu,
                                   Wgu, bgu, Wfvc, bfvc, uwb);
        kCf11<true><<<NB2, 512, 0, stream>>>(sup, qry, uwb, Wfvc, Wgvc, bgvc, Wfz, bfz, zAcc);
        kD<<<1, 1024, 0, stream>>>(zAcc, Wgz, bgz, out);
    }
}